// Round 3
// baseline (682.267 us; speedup 1.0000x reference)
//
#include <hip/hip_runtime.h>
#include <stdint.h>

#define NB 64
#define DD 256
#define HH 512
#define NGROUP 2048

typedef __attribute__((ext_vector_type(8))) _Float16 half8;
typedef __attribute__((ext_vector_type(4))) _Float16 half4;
typedef __attribute__((ext_vector_type(4))) float f32x4;

__device__ __forceinline__ half8 ld8(const _Float16* p) {
    return *reinterpret_cast<const half8*>(p);
}

// ---------------- precompute kernels ----------------

// G[d][e] = scale * sum_h Wq[d,h] * Wk[e,h]
__global__ void prep_G_kernel(const float* __restrict__ Wq, const float* __restrict__ Wk,
                              _Float16* __restrict__ G, float scale) {
    const int d = blockIdx.x;
    const int e = threadIdx.x;
    const float4* qa = reinterpret_cast<const float4*>(Wq + d * HH);
    const float4* ka = reinterpret_cast<const float4*>(Wk + e * HH);
    float s = 0.f;
    #pragma unroll 8
    for (int j = 0; j < HH / 4; ++j) {
        float4 a = qa[j], b = ka[j];
        s += a.x * b.x + a.y * b.y + a.z * b.z + a.w * b.w;
    }
    G[d * DD + e] = (_Float16)(s * scale);
}

// UT[o][coff + d] = sum_j Wv[d,j] * W1p[j,o]   (UT combined [512][512])
__global__ void prep_U_kernel(const float* __restrict__ Wv, const float* __restrict__ W1p,
                              _Float16* __restrict__ UT, int coff) {
    const int o = blockIdx.x;
    const int d = threadIdx.x;
    const float4* va = reinterpret_cast<const float4*>(Wv + d * HH);
    float s = 0.f;
    #pragma unroll 4
    for (int j4 = 0; j4 < HH / 4; ++j4) {
        float4 a = va[j4];
        const int j = j4 * 4;
        s += a.x * W1p[(j + 0) * HH + o];
        s += a.y * W1p[(j + 1) * HH + o];
        s += a.z * W1p[(j + 2) * HH + o];
        s += a.w * W1p[(j + 3) * HH + o];
    }
    UT[o * HH + coff + d] = (_Float16)s;
}

// W2T[k][h] = W2[h][k]
__global__ void prep_W2T_kernel(const float* __restrict__ W2, _Float16* __restrict__ W2T) {
    __shared__ float tile[32][33];
    const int bk = blockIdx.x * 32;
    const int bh = blockIdx.y * 32;
    const int tx = threadIdx.x & 31, ty = threadIdx.x >> 5;
    #pragma unroll
    for (int i = 0; i < 32; i += 8)
        tile[ty + i][tx] = W2[(bh + ty + i) * HH + bk + tx];
    __syncthreads();
    #pragma unroll
    for (int i = 0; i < 32; i += 8)
        W2T[(bk + ty + i) * HH + bh + tx] = (_Float16)tile[tx][ty + i];
}

// ---------------- main fused kernel ----------------
// LDS 80 KiB -> 2 blocks/CU:
//   X1 @ 0      [64][256] f16 swz  -> becomes g1
//   X2 @ 32768  [64][256] f16 swz  -> becomes g2
//   R  @ 65536  16 KiB: A-chunk [64][128] -> P [64][64] (@0) + XT scratch [32][64] (@8192) -> hc [64][128]
// swizzle: byte ^= (row&7)<<4 (16B granule spread over 8 bank-groups)

__device__ __forceinline__ int axX(int side, int row, int ec) {   // 512B rows
    return side * 32768 + row * 512 + ((2 * ec) ^ ((row & 7) << 4));
}
__device__ __forceinline__ int axR(int row, int ec) {             // 256B rows
    return 65536 + row * 256 + ((2 * ec) ^ ((row & 7) << 4));
}
__device__ __forceinline__ int axP(int row, int ec) {             // 128B rows @ R
    return 65536 + row * 128 + ((2 * ec) ^ ((row & 7) << 4));
}
__device__ __forceinline__ int axT(int row, int ec) {             // 128B rows @ R+8192
    return 65536 + 8192 + row * 128 + ((2 * ec) ^ ((row & 7) << 4));
}

__global__ __launch_bounds__(512, 4)
void fused_kernel(const float* __restrict__ x1g, const float* __restrict__ x2g,
                  const _Float16* __restrict__ G1, const _Float16* __restrict__ G2,
                  const _Float16* __restrict__ UT, const _Float16* __restrict__ W2T,
                  const float* __restrict__ b1, const float* __restrict__ b2,
                  float* __restrict__ out) {
    __shared__ __align__(16) char lds[81920];

    const int tid = threadIdx.x;
    const int lane = tid & 63;
    const int w = tid >> 6;        // wave 0..7
    const int c = lane & 15;
    const int kg = lane >> 4;
    const size_t g = blockIdx.x;
    const f32x4 z = {0.f, 0.f, 0.f, 0.f};

    // ---- Phase 0: stage x -> f16 swizzled LDS ----
    {
        const float4* s1 = reinterpret_cast<const float4*>(x1g) + g * (NB * DD / 4);
        const float4* s2 = reinterpret_cast<const float4*>(x2g) + g * (NB * DD / 4);
        #pragma unroll
        for (int it = 0; it < 4; ++it) {
            const int G_ = tid + 512 * it;
            const int row = G_ >> 5, cg = G_ & 31;
            float4 a0 = s1[row * 64 + cg * 2], a1 = s1[row * 64 + cg * 2 + 1];
            float4 b0 = s2[row * 64 + cg * 2], b1v = s2[row * 64 + cg * 2 + 1];
            half8 ha, hb;
            ha[0] = (_Float16)a0.x; ha[1] = (_Float16)a0.y; ha[2] = (_Float16)a0.z; ha[3] = (_Float16)a0.w;
            ha[4] = (_Float16)a1.x; ha[5] = (_Float16)a1.y; ha[6] = (_Float16)a1.z; ha[7] = (_Float16)a1.w;
            hb[0] = (_Float16)b0.x; hb[1] = (_Float16)b0.y; hb[2] = (_Float16)b0.z; hb[3] = (_Float16)b0.w;
            hb[4] = (_Float16)b1v.x; hb[5] = (_Float16)b1v.y; hb[6] = (_Float16)b1v.z; hb[7] = (_Float16)b1v.w;
            *reinterpret_cast<half8*>(lds + axX(0, row, cg * 8)) = ha;
            *reinterpret_cast<half8*>(lds + axX(1, row, cg * 8)) = hb;
        }
    }
    __syncthreads();

    // ---- Scores: S1 (waves 0-3), S2 (waves 4-7) in registers ----
    f32x4 Sacc[4] = {z, z, z, z};
    const int wn = w & 3;
    #pragma unroll
    for (int ai = 0; ai < 2; ++ai) {
        const _Float16* Gm = ai ? G2 : G1;
        const int xsrc = ai ? 0 : 1;   // A2 = X2@G1^T ; A1 = X1@G2^T
        const int xq   = ai ? 1 : 0;   // S1 = X1@A2^T ; S2 = X2@A1^T
        #pragma unroll
        for (int ci = 0; ci < 2; ++ci) {
            // A-chunk: cols d' = 128ci + 16w + c, all 64 rows m
            const _Float16* gp = Gm + (size_t)(128 * ci + 16 * w + c) * DD;
            half8 bf[8];
            #pragma unroll
            for (int ks = 0; ks < 8; ++ks) bf[ks] = ld8(gp + 32 * ks + 8 * kg);
            #pragma unroll
            for (int i = 0; i < 4; ++i) {
                f32x4 acc = z;
                #pragma unroll
                for (int ks = 0; ks < 8; ++ks) {
                    half8 af = *reinterpret_cast<const half8*>(lds + axX(xsrc, 16 * i + c, 32 * ks + 8 * kg));
                    acc = __builtin_amdgcn_mfma_f32_16x16x32_f16(af, bf[ks], acc, 0, 0, 0);
                }
                #pragma unroll
                for (int r = 0; r < 4; ++r)
                    *reinterpret_cast<_Float16*>(lds + axR(16 * i + 4 * kg + r, 16 * w + c)) = (_Float16)acc[r];
            }
            __syncthreads();
            if ((w >> 2) == ai) {
                #pragma unroll
                for (int ks = 0; ks < 4; ++ks) {
                    half8 af = *reinterpret_cast<const half8*>(lds + axX(xq, 16 * wn + c, 128 * ci + 32 * ks + 8 * kg));
                    #pragma unroll
                    for (int j = 0; j < 4; ++j) {
                        half8 bfr = *reinterpret_cast<const half8*>(lds + axR(16 * j + c, 32 * ks + 8 * kg));
                        Sacc[j] = __builtin_amdgcn_mfma_f32_16x16x32_f16(af, bfr, Sacc[j], 0, 0, 0);
                    }
                }
            }
            __syncthreads();
        }
    }

    // ---- Per side: softmax -> P (R[0:8K]); PV with in-place transpose -> g in X region ----
    #pragma unroll
    for (int s = 0; s < 2; ++s) {
        if ((w >> 2) == s) {
            #pragma unroll
            for (int r = 0; r < 4; ++r) {
                float m0 = fmaxf(fmaxf(Sacc[0][r], Sacc[1][r]), fmaxf(Sacc[2][r], Sacc[3][r]));
                m0 = fmaxf(m0, __shfl_xor(m0, 1));
                m0 = fmaxf(m0, __shfl_xor(m0, 2));
                m0 = fmaxf(m0, __shfl_xor(m0, 4));
                m0 = fmaxf(m0, __shfl_xor(m0, 8));
                float e0 = __expf(Sacc[0][r] - m0);
                float e1 = __expf(Sacc[1][r] - m0);
                float e2 = __expf(Sacc[2][r] - m0);
                float e3 = __expf(Sacc[3][r] - m0);
                float s0 = e0 + e1 + e2 + e3;
                s0 += __shfl_xor(s0, 1);
                s0 += __shfl_xor(s0, 2);
                s0 += __shfl_xor(s0, 4);
                s0 += __shfl_xor(s0, 8);
                const float inv = 1.f / s0;
                const int row = 16 * wn + 4 * kg + r;
                *reinterpret_cast<_Float16*>(lds + axP(row, 16 * 0 + c)) = (_Float16)(e0 * inv);
                *reinterpret_cast<_Float16*>(lds + axP(row, 16 * 1 + c)) = (_Float16)(e1 * inv);
                *reinterpret_cast<_Float16*>(lds + axP(row, 16 * 2 + c)) = (_Float16)(e2 * inv);
                *reinterpret_cast<_Float16*>(lds + axP(row, 16 * 3 + c)) = (_Float16)(e3 * inv);
            }
        }
        __syncthreads();

        // PV: g[n][d] = sum_m P[n][m] X[m][d], 8 chunks of 32 d-cols
        const int wr = w & 3, wc = (w >> 2) & 1;
        half8 af[2];
        #pragma unroll
        for (int ks = 0; ks < 2; ++ks)
            af[ks] = *reinterpret_cast<const half8*>(lds + axP(16 * wr + c, 32 * ks + 8 * kg));

        const int m_ = tid >> 3, qd = tid & 7;
        half4 v = *reinterpret_cast<const half4*>(lds + axX(s, m_, 4 * qd));
        #pragma unroll
        for (int ci = 0; ci < 8; ++ci) {
            // write transposed chunk to scratch
            #pragma unroll
            for (int e = 0; e < 4; ++e)
                *reinterpret_cast<_Float16*>(lds + axT(4 * qd + e, m_)) = v[e];
            __syncthreads();
            if (ci < 7) v = *reinterpret_cast<const half4*>(lds + axX(s, m_, (ci + 1) * 32 + 4 * qd));
            f32x4 acc = z;
            #pragma unroll
            for (int ks = 0; ks < 2; ++ks) {
                half8 bfr = *reinterpret_cast<const half8*>(lds + axT(16 * wc + c, 32 * ks + 8 * kg));
                acc = __builtin_amdgcn_mfma_f32_16x16x32_f16(af[ks], bfr, acc, 0, 0, 0);
            }
            __syncthreads();
            // write g chunk into the consumed column slice (same swizzle bijection)
            #pragma unroll
            for (int r = 0; r < 4; ++r)
                *reinterpret_cast<_Float16*>(lds + axX(s, 16 * wr + 4 * kg + r, 32 * ci + 16 * wc + c)) = (_Float16)acc[r];
        }
        __syncthreads();
    }

    // ---- MLP: h chunks of 128 cols via R; out^T accumulated in regs ----
    f32x4 oacc[4][4];
    #pragma unroll
    for (int i = 0; i < 4; ++i)
        #pragma unroll
        for (int j = 0; j < 4; ++j) oacc[i][j] = z;

    #pragma unroll
    for (int q = 0; q < 4; ++q) {
        f32x4 hacc[4] = {z, z, z, z};
        const int hcol = 128 * q + 16 * w + c;
        #pragma unroll
        for (int ks = 0; ks < 16; ++ks) {
            half8 bfr = ld8(UT + (size_t)hcol * HH + (ks >> 3) * 256 + 32 * (ks & 7) + 8 * kg);
            #pragma unroll
            for (int i = 0; i < 4; ++i) {
                half8 afr = *reinterpret_cast<const half8*>(lds + axX(ks >> 3, 16 * i + c, 32 * (ks & 7) + 8 * kg));
                hacc[i] = __builtin_amdgcn_mfma_f32_16x16x32_f16(afr, bfr, hacc[i], 0, 0, 0);
            }
        }
        const float bb = b1[hcol];
        #pragma unroll
        for (int i = 0; i < 4; ++i)
            #pragma unroll
            for (int r = 0; r < 4; ++r)
                *reinterpret_cast<_Float16*>(lds + axR(16 * i + 4 * kg + r, 16 * w + c)) =
                    (_Float16)fmaxf(hacc[i][r] + bb, 0.f);
        __syncthreads();
        #pragma unroll
        for (int ks = 0; ks < 4; ++ks) {
            half8 bfr2[4];
            #pragma unroll
            for (int nj = 0; nj < 4; ++nj)
                bfr2[nj] = *reinterpret_cast<const half8*>(lds + axR(16 * nj + c, 32 * ks + 8 * kg));
            #pragma unroll
            for (int i = 0; i < 4; ++i) {
                half8 af2 = ld8(W2T + (size_t)(64 * w + 16 * i + c) * HH + 128 * q + 32 * ks + 8 * kg);
                #pragma unroll
                for (int nj = 0; nj < 4; ++nj)
                    oacc[i][nj] = __builtin_amdgcn_mfma_f32_16x16x32_f16(af2, bfr2[nj], oacc[i][nj], 0, 0, 0);
            }
        }
        __syncthreads();
    }

    // ---- Epilogue: out^T regs -> coalesced float4 stores ----
    float* og = out + g * (size_t)(NB * HH);
    #pragma unroll
    for (int i = 0; i < 4; ++i) {
        const int ocol0 = 64 * w + 16 * i + 4 * kg;
        const float4 b2v = *reinterpret_cast<const float4*>(b2 + ocol0);
        #pragma unroll
        for (int nj = 0; nj < 4; ++nj) {
            float4 res;
            res.x = oacc[i][nj][0] + b2v.x;
            res.y = oacc[i][nj][1] + b2v.y;
            res.z = oacc[i][nj][2] + b2v.z;
            res.w = oacc[i][nj][3] + b2v.w;
            *reinterpret_cast<float4*>(og + (size_t)(16 * nj + c) * HH + ocol0) = res;
        }
    }
}

// ---------------- launch ----------------

extern "C" void kernel_launch(void* const* d_in, const int* in_sizes, int n_in,
                              void* d_out, int out_size, void* d_ws, size_t ws_size,
                              hipStream_t stream) {
    (void)in_sizes; (void)n_in; (void)out_size; (void)ws_size;
    const float* x1  = (const float*)d_in[0];
    const float* x2  = (const float*)d_in[1];
    const float* Wq1 = (const float*)d_in[2];
    const float* Wk1 = (const float*)d_in[3];
    const float* Wv1 = (const float*)d_in[4];
    const float* Wq2 = (const float*)d_in[5];
    const float* Wk2 = (const float*)d_in[6];
    const float* Wv2 = (const float*)d_in[7];
    const float* W1  = (const float*)d_in[8];
    const float* b1  = (const float*)d_in[9];
    const float* W2  = (const float*)d_in[10];
    const float* b2  = (const float*)d_in[11];
    float* out = (float*)d_out;

    char* ws = (char*)d_ws;
    _Float16* G1  = (_Float16*)(ws + 0);        // 131072
    _Float16* G2  = (_Float16*)(ws + 131072);   // 131072
    _Float16* UT  = (_Float16*)(ws + 262144);   // 524288 (combined [512][512])
    _Float16* W2T = (_Float16*)(ws + 786432);   // 524288

    const float scale = 0.0625f;  // D^-0.5

    prep_G_kernel<<<DD, DD, 0, stream>>>(Wq1, Wk2, G1, scale);
    prep_G_kernel<<<DD, DD, 0, stream>>>(Wq2, Wk1, G2, scale);
    prep_U_kernel<<<HH, DD, 0, stream>>>(Wv1, W1, UT, 0);
    prep_U_kernel<<<HH, DD, 0, stream>>>(Wv2, W1 + HH * HH, UT, 256);
    prep_W2T_kernel<<<dim3(16, 16), 256, 0, stream>>>(W2, W2T);

    fused_kernel<<<NGROUP, 512, 0, stream>>>(x1, x2, G1, G2, UT, W2T, b1, b2, out);
}